// Round 6
// baseline (77.641 us; speedup 1.0000x reference)
//
#include <hip/hip_runtime.h>

#define CUTOFF 5.0f
#define NB 32
#define LOG2E 1.4426950408889634f

typedef float f32x4 __attribute__((ext_vector_type(4)));

// Wave owns 16 edges. Phase 1: lanes 0-15 each compute one edge's scalars
// (r, phi, exp(-r)); index loads are nontemporal (streamed once) to keep L2
// for the coord table. Phase 2: two iterations; broadcast 8 edges' (er, phi)
// via __shfl, each lane computes 4 basis values with raw v_exp_f32 (exp2
// with pre-scaled beta) and stores one float4 -> 1024 B/wave, nontemporal.
// Tail handling is wave-uniform: only the last wave takes the masked path.
__global__ __launch_bounds__(256) void physnet_rbf_kernel(
    const float* __restrict__ coords,   // [N_NODES, 3]
    const int*   __restrict__ recv,     // [E]
    const int*   __restrict__ send,     // [E]
    const float* __restrict__ mu,       // [32]
    const float* __restrict__ beta,     // [32]
    float*       __restrict__ out,      // [E, 32]
    int n_edges)
{
    int lane  = threadIdx.x & 63;
    int wid   = blockIdx.x * (blockDim.x >> 6) + (threadIdx.x >> 6);
    int ebase = wid * 16;
    bool full = (ebase + 16 <= n_edges);        // wave-uniform

    // -------- phase 1: per-edge scalars on lanes 0-15 --------
    float er = 0.0f, phi = 0.0f;
    if (lane < 16 && (full || ebase + lane < n_edges)) {
        int e = ebase + lane;
        int ir = __builtin_nontemporal_load(recv + e);
        int is = __builtin_nontemporal_load(send + e);
        const float* cr = coords + (size_t)ir * 3;
        const float* cs = coords + (size_t)is * 3;
        float dx = cr[0] - cs[0];
        float dy = cr[1] - cs[1];
        float dz = cr[2] - cs[2];
        float r  = sqrtf(dx * dx + dy * dy + dz * dz);
        float u  = r * (1.0f / CUTOFF);
        float u3 = u * u * u;
        phi = 1.0f + u3 * (-10.0f + u * (15.0f - 6.0f * u));
        er  = __builtin_amdgcn_exp2f(-r * LOG2E);   // exp(-r)
    }

    // -------- phase 2: RBF + dense stores --------
    int k4 = (lane & 7) << 2;                   // basis offset 0,4,...,28
    float4 m = *reinterpret_cast<const float4*>(mu + k4);
    float4 b = *reinterpret_cast<const float4*>(beta + k4);
    // pre-scale: exp(-b*d^2) == exp2(b2*d^2), b2 = -b*log2(e)  (hoisted)
    float4 b2;
    b2.x = -b.x * LOG2E; b2.y = -b.y * LOG2E;
    b2.z = -b.z * LOG2E; b2.w = -b.w * LOG2E;
    int sub = lane >> 3;

    #pragma unroll
    for (int i = 0; i < 2; ++i) {
        int src = i * 8 + sub;
        float er_i  = __shfl(er,  src);
        float phi_i = __shfl(phi, src);
        int eo = ebase + src;
        if (full || eo < n_edges) {
            f32x4 o;
            float d0 = er_i - m.x; o.x = __builtin_amdgcn_exp2f(b2.x * d0 * d0) * phi_i;
            float d1 = er_i - m.y; o.y = __builtin_amdgcn_exp2f(b2.y * d1 * d1) * phi_i;
            float d2 = er_i - m.z; o.z = __builtin_amdgcn_exp2f(b2.z * d2 * d2) * phi_i;
            float d3 = er_i - m.w; o.w = __builtin_amdgcn_exp2f(b2.w * d3 * d3) * phi_i;
            __builtin_nontemporal_store(
                o, reinterpret_cast<f32x4*>(out + (size_t)eo * NB + k4));
        }
    }
}

extern "C" void kernel_launch(void* const* d_in, const int* in_sizes, int n_in,
                              void* d_out, int out_size, void* d_ws, size_t ws_size,
                              hipStream_t stream) {
    const float* coords = (const float*)d_in[0];
    const int*   recv   = (const int*)d_in[1];
    const int*   send   = (const int*)d_in[2];
    const float* mu     = (const float*)d_in[3];
    const float* beta   = (const float*)d_in[4];
    float*       out    = (float*)d_out;

    int n_edges = in_sizes[1];                  // receivers flat count = E
    // 16 edges per wave, 4 waves per block -> 64 edges per block
    int block = 256;
    int grid = (n_edges + 63) / 64;

    physnet_rbf_kernel<<<grid, block, 0, stream>>>(coords, recv, send, mu, beta,
                                                   out, n_edges);
}

// Round 7
// 46.742 us; speedup vs baseline: 1.6610x; 1.6610x over previous
//
#include <hip/hip_runtime.h>

#define CUTOFF 5.0f
#define NB 32
#define LOG2E 1.4426950408889634f

typedef float f32x4 __attribute__((ext_vector_type(4)));

// Wave owns 16 edges. Phase 1: lanes 0-15 each compute one edge's scalars
// (r, phi, exp(-r)). Phase 2: two iterations; broadcast 8 edges' (er, phi)
// via __shfl, each lane computes 4 basis values with raw v_exp_f32 (exp2
// with pre-scaled beta) and stores one float4 -> 1024 B/wave, nontemporal.
// NOTE (R6 post-mortem): nontemporal INDEX LOADS regressed 47->78 us — nt
// loads bypass L1/L2 and expose full HBM latency on the 16-lane phase-1
// path. Keep nt for the write-once stores only.
__global__ __launch_bounds__(256) void physnet_rbf_kernel(
    const float* __restrict__ coords,   // [N_NODES, 3]
    const int*   __restrict__ recv,     // [E]
    const int*   __restrict__ send,     // [E]
    const float* __restrict__ mu,       // [32]
    const float* __restrict__ beta,     // [32]
    float*       __restrict__ out,      // [E, 32]
    int n_edges)
{
    int lane  = threadIdx.x & 63;
    int wid   = blockIdx.x * (blockDim.x >> 6) + (threadIdx.x >> 6);
    int ebase = wid * 16;

    // -------- phase 1: per-edge scalars on lanes 0-15 --------
    float er = 0.0f, phi = 0.0f;
    if (lane < 16) {
        int e = ebase + lane;
        if (e < n_edges) {
            int ir = recv[e];
            int is = send[e];
            const float* cr = coords + (size_t)ir * 3;
            const float* cs = coords + (size_t)is * 3;
            float dx = cr[0] - cs[0];
            float dy = cr[1] - cs[1];
            float dz = cr[2] - cs[2];
            float r  = sqrtf(dx * dx + dy * dy + dz * dz);
            float u  = r * (1.0f / CUTOFF);
            float u3 = u * u * u;
            phi = 1.0f + u3 * (-10.0f + u * (15.0f - 6.0f * u));
            er  = __builtin_amdgcn_exp2f(-r * LOG2E);   // exp(-r)
        }
    }

    // -------- phase 2: RBF + dense stores --------
    int k4 = (lane & 7) << 2;                   // basis offset 0,4,...,28
    float4 m = *reinterpret_cast<const float4*>(mu + k4);
    float4 b = *reinterpret_cast<const float4*>(beta + k4);
    // pre-scale: exp(-b*d^2) == exp2(b2*d^2), b2 = -b*log2(e)  (hoisted)
    float4 b2;
    b2.x = -b.x * LOG2E; b2.y = -b.y * LOG2E;
    b2.z = -b.z * LOG2E; b2.w = -b.w * LOG2E;
    int sub = lane >> 3;

    #pragma unroll
    for (int i = 0; i < 2; ++i) {
        int src = i * 8 + sub;
        float er_i  = __shfl(er,  src);
        float phi_i = __shfl(phi, src);
        int eo = ebase + src;
        if (eo < n_edges) {
            f32x4 o;
            float d0 = er_i - m.x; o.x = __builtin_amdgcn_exp2f(b2.x * d0 * d0) * phi_i;
            float d1 = er_i - m.y; o.y = __builtin_amdgcn_exp2f(b2.y * d1 * d1) * phi_i;
            float d2 = er_i - m.z; o.z = __builtin_amdgcn_exp2f(b2.z * d2 * d2) * phi_i;
            float d3 = er_i - m.w; o.w = __builtin_amdgcn_exp2f(b2.w * d3 * d3) * phi_i;
            __builtin_nontemporal_store(
                o, reinterpret_cast<f32x4*>(out + (size_t)eo * NB + k4));
        }
    }
}

extern "C" void kernel_launch(void* const* d_in, const int* in_sizes, int n_in,
                              void* d_out, int out_size, void* d_ws, size_t ws_size,
                              hipStream_t stream) {
    const float* coords = (const float*)d_in[0];
    const int*   recv   = (const int*)d_in[1];
    const int*   send   = (const int*)d_in[2];
    const float* mu     = (const float*)d_in[3];
    const float* beta   = (const float*)d_in[4];
    float*       out    = (float*)d_out;

    int n_edges = in_sizes[1];                  // receivers flat count = E
    // 16 edges per wave, 4 waves per block -> 64 edges per block
    int block = 256;
    int grid = (n_edges + 63) / 64;

    physnet_rbf_kernel<<<grid, block, 0, stream>>>(coords, recv, send, mu, beta,
                                                   out, n_edges);
}